// Round 2
// baseline (263.242 us; speedup 1.0000x reference)
//
#include <hip/hip_runtime.h>

#define N_EDGE 40000

// ---------------- path table (compile-time, mirrors Python _PATHS order) ----
// p : (l1,l2,l3)  row_off  cg_off(dense)   total cg floats = 1875, rows = 99

__device__ float g_cg[1875];

__device__ const int PL1[23] = {0,0,0,0, 1,1,1,1,1,1, 2,2,2,2,2,2,2, 3,3,3,3,3,3};
__device__ const int PL2[23] = {0,1,2,3, 0,1,1,2,2,3, 0,1,1,2,2,3,3, 0,1,2,2,3,3};
__device__ const int PL3[23] = {0,1,2,3, 1,0,2,1,3,2, 2,1,3,0,2,1,3, 3,2,1,3,0,2};
__device__ const int PCO[23] = {0,1,10,35, 84,93,102,147,192,297,
                                402,427,472,577,602,727,832,
                                1077,1126,1231,1336,1581,1630};

// ---------------- device CG math (mirrors the Python reference) -------------
__device__ inline double dfact(int n) {
    double r = 1.0;
    for (int i = 2; i <= n; ++i) r *= (double)i;
    return r;
}
__device__ inline int imax2(int a, int b) { return a > b ? a : b; }
__device__ inline int imin2(int a, int b) { return a < b ? a : b; }

__device__ double cg_coeff(int j1, int m1, int j2, int m2, int j3, int m3) {
    if (m3 != m1 + m2) return 0.0;
    int vmin = imax2(0, imax2(j2 - j3 - m1, j1 - j3 + m2));
    int vmax = imin2(j1 + j2 - j3, imin2(j1 - m1, j2 + m2));
    if (vmax < vmin) return 0.0;
    double pref = sqrt((double)(2 * j3 + 1) * dfact(j3 + j1 - j2) * dfact(j3 - j1 + j2) *
                       dfact(j1 + j2 - j3) / dfact(j1 + j2 + j3 + 1));
    pref *= sqrt(dfact(j3 + m3) * dfact(j3 - m3) * dfact(j1 - m1) * dfact(j1 + m1) *
                 dfact(j2 - m2) * dfact(j2 + m2));
    double s = 0.0;
    for (int v = vmin; v <= vmax; ++v) {
        double term = 1.0 / (dfact(v) * dfact(j1 + j2 - j3 - v) * dfact(j1 - m1 - v) *
                             dfact(j2 + m2 - v) * dfact(j3 - j2 + m1 + v) * dfact(j3 - j1 - m2 + v));
        s += (v & 1) ? -term : term;
    }
    return pref * s;
}

// q(l): complex (2l+1)x(2l+1), row-major, stride n=2l+1
__device__ void make_q(int l, double* qre, double* qim) {
    int n = 2 * l + 1;
    for (int i = 0; i < n * n; ++i) { qre[i] = 0.0; qim[i] = 0.0; }
    const double s = 0.70710678118654752440;
    for (int m = -l; m < 0; ++m) {
        int am = -m;
        qre[(l + m) * n + (l + am)] = s;
        qim[(l + m) * n + (l - am)] = -s;
    }
    qre[l * n + l] = 1.0;
    for (int m = 1; m <= l; ++m) {
        double sgn = (m & 1) ? -1.0 : 1.0;
        qre[(l + m) * n + (l + m)] = sgn * s;
        qim[(l + m) * n + (l - m)] = sgn * s;
    }
    // multiply by (-i)^l
    int ph = l & 3;
    if (ph) {
        for (int i = 0; i < n * n; ++i) {
            double re = qre[i], im = qim[i];
            if (ph == 1)      { qre[i] =  im; qim[i] = -re; }
            else if (ph == 2) { qre[i] = -re; qim[i] = -im; }
            else              { qre[i] = -im; qim[i] =  re; }
        }
    }
}

// one block per path: compute real CG tensor, normalize, write to g_cg
__global__ void cg_setup_kernel() {
    const int p  = blockIdx.x;
    const int l1 = PL1[p], l2 = PL2[p], l3 = PL3[p];
    const int n1 = 2 * l1 + 1, n2 = 2 * l2 + 1, n3 = 2 * l3 + 1;
    const int nD = n1 * n2 * n3;
    const int tid = threadIdx.x;

    __shared__ double cgc[343];
    __shared__ double q1re[49], q1im[49], q2re[49], q2im[49], q3re[49], q3im[49];
    __shared__ double red[256];

    for (int t = tid; t < nD; t += blockDim.x) {
        int a = t / (n2 * n3);
        int b = (t / n3) % n2;
        int cc = t % n3;
        cgc[t] = cg_coeff(l1, a - l1, l2, b - l2, l3, cc - l3);
    }
    if (tid == 0) {
        make_q(l1, q1re, q1im);
        make_q(l2, q2re, q2im);
        make_q(l3, q3re, q3im);
    }
    __syncthreads();

    double dre = 0.0, dim = 0.0;
    if (tid < nD) {
        const int i = tid / (n2 * n3);
        const int j = (tid / n3) % n2;
        const int k = tid % n3;
        for (int a = 0; a < n1; ++a) {
            double q1r = q1re[i * n1 + a], q1i = q1im[i * n1 + a];
            if (q1r == 0.0 && q1i == 0.0) continue;
            for (int b = 0; b < n2; ++b) {
                double q2r = q2re[j * n2 + b], q2i = q2im[j * n2 + b];
                if (q2r == 0.0 && q2i == 0.0) continue;
                double wr = q1r * q2r - q1i * q2i;
                double wi = q1r * q2i + q1i * q2r;
                for (int cc = 0; cc < n3; ++cc) {
                    double g = cgc[(a * n2 + b) * n3 + cc];
                    if (g == 0.0) continue;
                    double q3r = q3re[k * n3 + cc];
                    double q3i = -q3im[k * n3 + cc];  // conj
                    dre += (wr * q3r - wi * q3i) * g;
                    dim += (wr * q3i + wi * q3r) * g;
                }
            }
        }
    }

    // block reduction: sum of squares of real part, then imag part
    red[tid] = (tid < nD) ? dre * dre : 0.0;
    __syncthreads();
    for (int s = 128; s > 0; s >>= 1) {
        if (tid < s) red[tid] += red[tid + s];
        __syncthreads();
    }
    double sum_re = red[0];
    __syncthreads();
    red[tid] = (tid < nD) ? dim * dim : 0.0;
    __syncthreads();
    for (int s = 128; s > 0; s >>= 1) {
        if (tid < s) red[tid] += red[tid + s];
        __syncthreads();
    }
    double sum_im = red[0];

    bool use_re = (sum_re >= sum_im);
    double nrm = sqrt(use_re ? sum_re : sum_im);
    if (tid < nD) {
        double v = (use_re ? dre : dim) / nrm;
        g_cg[PCO[p] + tid] = (float)v;
    }
}

// ---------------- main tensor-product kernel --------------------------------
// |m|-selection filter: real CG can be nonzero only if |m3| == |m1|+|m2|
// or |m3| == ||m1|-|m2||  (necessary condition; folds at compile time)
template <int L1, int L2, int L3, int RO, int CO>
__device__ __forceinline__ void do_path2(const float* xv0, const float* xv1,
                                         const float* yv0, const float* yv1,
                                         const float* cg, float* o0, float* o1) {
    constexpr int N1 = 2 * L1 + 1, N2 = 2 * L2 + 1, N3 = 2 * L3 + 1;
    constexpr int X0 = L1 * L1, Y0 = L2 * L2;
    float a0[N3], a1[N3];
#pragma unroll
    for (int k = 0; k < N3; ++k) { a0[k] = 0.f; a1[k] = 0.f; }
#pragma unroll
    for (int i = 0; i < N1; ++i) {
#pragma unroll
        for (int j = 0; j < N2; ++j) {
            float t0 = xv0[X0 + i] * yv0[Y0 + j];
            float t1 = xv1[X0 + i] * yv1[Y0 + j];
#pragma unroll
            for (int k = 0; k < N3; ++k) {
                const int m1 = i - L1, m2 = j - L2, m3 = k - L3;
                const int am1 = m1 < 0 ? -m1 : m1;
                const int am2 = m2 < 0 ? -m2 : m2;
                const int am3 = m3 < 0 ? -m3 : m3;
                const int d = am1 - am2;
                const int ad = d < 0 ? -d : d;
                if (am3 == am1 + am2 || am3 == ad) {
                    float cgv = cg[CO + (i * N2 + j) * N3 + k];
                    a0[k] += cgv * t0;
                    a1[k] += cgv * t1;
                }
            }
        }
    }
#pragma unroll
    for (int k = 0; k < N3; ++k) {
        o0[(RO + k) * 64] = a0[k];
        o1[(RO + k) * 64] = a1[k];
    }
}

__global__ __launch_bounds__(256) void tp_main_kernel(const float* __restrict__ x,
                                                      const float* __restrict__ y,
                                                      float* __restrict__ out) {
    __shared__ float cg_s[1875];
    for (int t = threadIdx.x; t < 1875; t += 256) cg_s[t] = g_cg[t];
    __syncthreads();

    const int wave = threadIdx.x >> 6;
    const int c    = threadIdx.x & 63;
    const int e0   = blockIdx.x * 8 + wave * 2;   // 4 waves x 2 edges = 8 edges/block
    const int e1   = e0 + 1;

    float xv0[16], xv1[16], yv0[16], yv1[16];
    const float* xp0 = x + (size_t)e0 * 1024 + c;
    const float* xp1 = x + (size_t)e1 * 1024 + c;
#pragma unroll
    for (int i = 0; i < 16; ++i) { xv0[i] = xp0[i * 64]; xv1[i] = xp1[i * 64]; }
    const float* yp0 = y + (size_t)e0 * 16;
    const float* yp1 = y + (size_t)e1 * 16;
#pragma unroll
    for (int j = 0; j < 16; ++j) { yv0[j] = yp0[j]; yv1[j] = yp1[j]; }

    float* o0 = out + (size_t)e0 * 99 * 64 + c;
    float* o1 = out + (size_t)e1 * 99 * 64 + c;

    do_path2<0,0,0,  0,    0>(xv0, xv1, yv0, yv1, cg_s, o0, o1);
    do_path2<0,1,1,  1,    1>(xv0, xv1, yv0, yv1, cg_s, o0, o1);
    do_path2<0,2,2,  4,   10>(xv0, xv1, yv0, yv1, cg_s, o0, o1);
    do_path2<0,3,3,  9,   35>(xv0, xv1, yv0, yv1, cg_s, o0, o1);
    do_path2<1,0,1, 16,   84>(xv0, xv1, yv0, yv1, cg_s, o0, o1);
    do_path2<1,1,0, 19,   93>(xv0, xv1, yv0, yv1, cg_s, o0, o1);
    do_path2<1,1,2, 20,  102>(xv0, xv1, yv0, yv1, cg_s, o0, o1);
    do_path2<1,2,1, 25,  147>(xv0, xv1, yv0, yv1, cg_s, o0, o1);
    do_path2<1,2,3, 28,  192>(xv0, xv1, yv0, yv1, cg_s, o0, o1);
    do_path2<1,3,2, 35,  297>(xv0, xv1, yv0, yv1, cg_s, o0, o1);
    do_path2<2,0,2, 40,  402>(xv0, xv1, yv0, yv1, cg_s, o0, o1);
    do_path2<2,1,1, 45,  427>(xv0, xv1, yv0, yv1, cg_s, o0, o1);
    do_path2<2,1,3, 48,  472>(xv0, xv1, yv0, yv1, cg_s, o0, o1);
    do_path2<2,2,0, 55,  577>(xv0, xv1, yv0, yv1, cg_s, o0, o1);
    do_path2<2,2,2, 56,  602>(xv0, xv1, yv0, yv1, cg_s, o0, o1);
    do_path2<2,3,1, 61,  727>(xv0, xv1, yv0, yv1, cg_s, o0, o1);
    do_path2<2,3,3, 64,  832>(xv0, xv1, yv0, yv1, cg_s, o0, o1);
    do_path2<3,0,3, 71, 1077>(xv0, xv1, yv0, yv1, cg_s, o0, o1);
    do_path2<3,1,2, 78, 1126>(xv0, xv1, yv0, yv1, cg_s, o0, o1);
    do_path2<3,2,1, 83, 1231>(xv0, xv1, yv0, yv1, cg_s, o0, o1);
    do_path2<3,2,3, 86, 1336>(xv0, xv1, yv0, yv1, cg_s, o0, o1);
    do_path2<3,3,0, 93, 1581>(xv0, xv1, yv0, yv1, cg_s, o0, o1);
    do_path2<3,3,2, 94, 1630>(xv0, xv1, yv0, yv1, cg_s, o0, o1);
}

// ---------------- launch ----------------------------------------------------
extern "C" void kernel_launch(void* const* d_in, const int* in_sizes, int n_in,
                              void* d_out, int out_size, void* d_ws, size_t ws_size,
                              hipStream_t stream) {
    const float* x = (const float*)d_in[0];
    const float* y = (const float*)d_in[1];
    float* out = (float*)d_out;

    cg_setup_kernel<<<dim3(23), dim3(256), 0, stream>>>();
    // 8 edges per block (4 waves x 2 edges); 40000 / 8 = 5000 blocks exactly
    tp_main_kernel<<<dim3(N_EDGE / 8), dim3(256), 0, stream>>>(x, y, out);
}